// Round 1
// baseline (614.669 us; speedup 1.0000x reference)
//
#include <hip/hip_runtime.h>
#include <math.h>

#define HW   65536
#define TNUM 60
#define NPRED 600
#define NCLS 91

// ---------------- wave/block reduction helpers ----------------
__device__ inline float wsum(float v) {
#pragma unroll
    for (int o = 32; o; o >>= 1) v += __shfl_xor(v, o);
    return v;
}
__device__ inline float wmaxr(float v) {
#pragma unroll
    for (int o = 32; o; o >>= 1) v = fmaxf(v, __shfl_xor(v, o));
    return v;
}
__device__ inline float wminr(float v) {
#pragma unroll
    for (int o = 32; o; o >>= 1) v = fminf(v, __shfl_xor(v, o));
    return v;
}

// ---------------- kernel A1: pack target masks into per-pixel bitmask ----------------
__global__ void hm_pack_tbits(const int* __restrict__ tgt_masks,
                              unsigned long long* __restrict__ tbits) {
    int pix = blockIdx.x * blockDim.x + threadIdx.x;
    if (pix >= HW) return;
    unsigned long long b = 0ull;
#pragma unroll
    for (int j = 0; j < TNUM; ++j) {
        if (tgt_masks[j * HW + pix] != 0) b |= (1ull << j);
    }
    tbits[pix] = b;
}

// ---------------- kernel A2: per-target sum + masks_to_boxes ----------------
__global__ void hm_tgt_stats(const int* __restrict__ tgt_masks,
                             float* __restrict__ tsum, float* __restrict__ tbox) {
    int j = blockIdx.x;
    int tid = threadIdx.x;
    const int* tm = tgt_masks + (size_t)j * HW;
    float cnt = 0.f;
    float xmax = -INFINITY, ymax = -INFINITY, xmin = INFINITY, ymin = INFINITY;
    for (int pix = tid; pix < HW; pix += 256) {
        float t = (float)tm[pix];
        float xf = (float)(pix & 255), yf = (float)(pix >> 8);
        float xm = t * xf, ym = t * yf;
        cnt += t;
        xmax = fmaxf(xmax, xm);
        ymax = fmaxf(ymax, ym);
        bool nz = (t != 0.f);
        xmin = fminf(xmin, nz ? xm : 1e8f);
        ymin = fminf(ymin, nz ? ym : 1e8f);
    }
    cnt = wsum(cnt);
    xmax = wmaxr(xmax); ymax = wmaxr(ymax);
    xmin = wminr(xmin); ymin = wminr(ymin);
    __shared__ float s[5][4];
    int wave = tid >> 6, lane = tid & 63;
    if (lane == 0) {
        s[0][wave] = cnt; s[1][wave] = xmax; s[2][wave] = ymax;
        s[3][wave] = xmin; s[4][wave] = ymin;
    }
    __syncthreads();
    if (tid == 0) {
        float c = s[0][0] + s[0][1] + s[0][2] + s[0][3];
        float xM = fmaxf(fmaxf(s[1][0], s[1][1]), fmaxf(s[1][2], s[1][3]));
        float yM = fmaxf(fmaxf(s[2][0], s[2][1]), fmaxf(s[2][2], s[2][3]));
        float xm2 = fminf(fminf(s[3][0], s[3][1]), fminf(s[3][2], s[3][3]));
        float ym2 = fminf(fminf(s[4][0], s[4][1]), fminf(s[4][2], s[4][3]));
        tsum[j] = c;
        tbox[j * 4 + 0] = xm2;  // x_min
        tbox[j * 4 + 1] = ym2;  // y_min
        tbox[j * 4 + 2] = xM;   // x_max
        tbox[j * 4 + 3] = yM;   // y_max
    }
}

// ---------------- kernel B: heavy per-pred-mask pass ----------------
// One block per pred mask. Computes:
//   dot_p[n][j]  = sum_pix p * t_j          (p = sigmoid(mask))
//   dot_f[n][j]  = sum_pix (pos-neg) * t_j  (focal per-pixel terms)
//   sum_p[n], sum_neg[n]
//   masks_to_boxes(pred_mask n) -> pbox[n][4] (xmin,ymin,xmax,ymax)
__launch_bounds__(256, 1)
__global__ void hm_pred_heavy(const float* __restrict__ pred_masks,
                              const unsigned long long* __restrict__ tbits,
                              float* __restrict__ dot_p, float* __restrict__ dot_f,
                              float* __restrict__ sum_p, float* __restrict__ sum_neg,
                              float* __restrict__ pbox) {
    int n = blockIdx.x;
    int tid = threadIdx.x;
    const float4* mrow = (const float4*)(pred_masks + (size_t)n * HW);
    const ulonglong2* tb2 = (const ulonglong2*)tbits;

    float accp[TNUM], accf[TNUM];
#pragma unroll
    for (int j = 0; j < TNUM; ++j) { accp[j] = 0.f; accf[j] = 0.f; }
    float sp = 0.f, sneg = 0.f;
    float xmax = -INFINITY, ymax = -INFINITY, xmin = INFINITY, ymin = INFINITY;

    for (int c = tid; c < HW / 4; c += 256) {
        float4 m4 = mrow[c];
        ulonglong2 tba = tb2[2 * c];
        ulonglong2 tbb = tb2[2 * c + 1];
        float mv[4] = {m4.x, m4.y, m4.z, m4.w};
        unsigned long long tbv[4] = {tba.x, tba.y, tbb.x, tbb.y};
        int pix0 = 4 * c;
#pragma unroll
        for (int k = 0; k < 4; ++k) {
            float x = mv[k];
            int pix = pix0 + k;
            float xf = (float)(pix & 255), yf = (float)(pix >> 8);
            // masks_to_boxes partials
            float xm = x * xf, ym = x * yf;
            xmax = fmaxf(xmax, xm);
            ymax = fmaxf(ymax, ym);
            bool nz = (x != 0.f);
            xmin = fminf(xmin, nz ? xm : 1e8f);
            ymin = fminf(ymin, nz ? ym : 1e8f);
            // sigmoid + focal terms (softplus forms)
            float ex = __expf(x);
            float p = __fdividef(ex, 1.f + ex);
            float spx = __logf(1.f + ex);   // -log(1-p)
            float spmx = spx - x;           // -log(p)
            float om = 1.f - p;
            float pos = 0.25f * om * om * spmx;
            float neg = 0.75f * p * p * spx;
            float f = pos - neg;
            sp += p;
            sneg += neg;
            unsigned lo = (unsigned)tbv[k];
            unsigned hi = (unsigned)(tbv[k] >> 32);
#pragma unroll
            for (int j = 0; j < 32; ++j) {
                float bf = (float)((lo >> j) & 1u);
                accp[j] += p * bf;
                accf[j] += f * bf;
            }
#pragma unroll
            for (int j = 0; j < TNUM - 32; ++j) {
                float bf = (float)((hi >> j) & 1u);
                accp[32 + j] += p * bf;
                accf[32 + j] += f * bf;
            }
        }
    }

    // wave-level butterfly reductions (all lanes end with the wave total)
#pragma unroll
    for (int j = 0; j < TNUM; ++j) { accp[j] = wsum(accp[j]); accf[j] = wsum(accf[j]); }
    sp = wsum(sp); sneg = wsum(sneg);
    xmax = wmaxr(xmax); ymax = wmaxr(ymax);
    xmin = wminr(xmin); ymin = wminr(ymin);

    // cross-wave via LDS: layout [wave][126]
    __shared__ float lred[4][128];
    int wave = tid >> 6, lane = tid & 63;
    if (lane == 0) {
#pragma unroll
        for (int j = 0; j < TNUM; ++j) {
            lred[wave][j] = accp[j];
            lred[wave][TNUM + j] = accf[j];
        }
        lred[wave][120] = sp;
        lred[wave][121] = sneg;
        lred[wave][122] = xmax;
        lred[wave][123] = ymax;
        lred[wave][124] = xmin;
        lred[wave][125] = ymin;
    }
    __syncthreads();
    if (tid < 126) {
        float a = lred[0][tid], b = lred[1][tid], c2 = lred[2][tid], d = lred[3][tid];
        if (tid < 122) {
            float s = a + b + c2 + d;
            if (tid < TNUM) dot_p[(size_t)n * TNUM + tid] = s;
            else if (tid < 120) dot_f[(size_t)n * TNUM + (tid - TNUM)] = s;
            else if (tid == 120) sum_p[n] = s;
            else sum_neg[n] = s;
        } else if (tid == 122) {
            pbox[n * 4 + 2] = fmaxf(fmaxf(a, b), fmaxf(c2, d));  // x_max
        } else if (tid == 123) {
            pbox[n * 4 + 3] = fmaxf(fmaxf(a, b), fmaxf(c2, d));  // y_max
        } else if (tid == 124) {
            pbox[n * 4 + 0] = fminf(fminf(a, b), fminf(c2, d));  // x_min
        } else {
            pbox[n * 4 + 1] = fminf(fminf(a, b), fminf(c2, d));  // y_min
        }
    }
}

// ---------------- combine ----------------
__device__ inline float giou_from_xyxy(float ax0, float ay0, float ax1, float ay1,
                                       float bx0, float by0, float bx1, float by1) {
    float area1 = (ax1 - ax0) * (ay1 - ay0);
    float area2 = (bx1 - bx0) * (by1 - by0);
    float ltx = fmaxf(ax0, bx0), lty = fmaxf(ay0, by0);
    float rbx = fminf(ax1, bx1), rby = fminf(ay1, by1);
    float iw = fmaxf(rbx - ltx, 0.f), ih = fmaxf(rby - lty, 0.f);
    float inter = iw * ih;
    float uni = area1 + area2 - inter;
    float iou = inter / uni;
    float ex0 = fminf(ax0, bx0), ey0 = fminf(ay0, by0);
    float ex1 = fmaxf(ax1, bx1), ey1 = fmaxf(ay1, by1);
    float ew = fmaxf(ex1 - ex0, 0.f), eh = fmaxf(ey1 - ey0, 0.f);
    float ae = ew * eh;
    return iou - (ae - uni) / ae;
}

__device__ inline float giou_from_cxcywh(float acx, float acy, float aw, float ah,
                                         float bcx, float bcy, float bw, float bh) {
    return giou_from_xyxy(acx - 0.5f * aw, acy - 0.5f * ah, acx + 0.5f * aw, acy + 0.5f * ah,
                          bcx - 0.5f * bw, bcy - 0.5f * bh, bcx + 0.5f * bw, bcy + 0.5f * bh);
}

__global__ void hm_combine(const float* __restrict__ pred_logits,
                           const float* __restrict__ pred_boxes,
                           const float* __restrict__ tgt_boxes,
                           const int* __restrict__ tgt_ids,
                           const float* __restrict__ dot_p, const float* __restrict__ dot_f,
                           const float* __restrict__ sum_p, const float* __restrict__ sum_neg,
                           const float* __restrict__ pbox, const float* __restrict__ tsum,
                           const float* __restrict__ tbox, float* __restrict__ out) {
    int idx = blockIdx.x * blockDim.x + threadIdx.x;
    if (idx >= NPRED * TNUM) return;
    int n = idx / TNUM, j = idx % TNUM;

    // L1 bbox cost
    float4 ob = ((const float4*)pred_boxes)[n];
    float4 tb = ((const float4*)tgt_boxes)[j];
    float cbbox = fabsf(ob.x - tb.x) + fabsf(ob.y - tb.y) + fabsf(ob.z - tb.z) + fabsf(ob.w - tb.w);

    // GIoU cost (boxes are cxcywh)
    float cgiou = -giou_from_cxcywh(ob.x, ob.y, ob.z, ob.w, tb.x, tb.y, tb.z, tb.w);

    // focal classification cost
    int id = tgt_ids[j];
    float lg = pred_logits[(size_t)n * NCLS + id];
    float e = __expf(lg);
    float pr = __fdividef(e, 1.f + e);
    float poscc = 0.25f * (1.f - pr) * (1.f - pr) * (-__logf(pr + 1e-8f));
    float negcc = 0.75f * pr * pr * (-__logf(1.f - pr + 1e-8f));
    float cclass = poscc - negcc;

    // GIoU on mask-derived "boxes" (faithfully fed through cxcywh conversion)
    float pxm = pbox[n * 4 + 0], pym = pbox[n * 4 + 1], pxM = pbox[n * 4 + 2], pyM = pbox[n * 4 + 3];
    float txm = tbox[j * 4 + 0], tym = tbox[j * 4 + 1], txM = tbox[j * 4 + 2], tyM = tbox[j * 4 + 3];
    float cm2b = -giou_from_cxcywh(pxm, pym, pxM, pyM, txm, tym, txM, tyM);

    // dice
    float dp = dot_p[idx];
    float un = sum_p[n] + tsum[j];
    float cdice = 1.f - (2.f * dp + 1e-5f) / (un + 1e-5f);

    // mask focal
    float cfocal = (dot_f[idx] + sum_neg[n]) * (1.0f / (float)HW);

    out[idx] = cbbox + cclass + cgiou + cm2b + cdice + cfocal;
}

// ---------------- launcher ----------------
extern "C" void kernel_launch(void* const* d_in, const int* in_sizes, int n_in,
                              void* d_out, int out_size, void* d_ws, size_t ws_size,
                              hipStream_t stream) {
    const float* pred_logits = (const float*)d_in[0];
    const float* pred_boxes  = (const float*)d_in[1];
    const float* pred_masks  = (const float*)d_in[2];
    const float* tgt_boxes   = (const float*)d_in[3];
    const int*   tgt_ids     = (const int*)d_in[4];
    const int*   tgt_masks   = (const int*)d_in[5];
    float* out = (float*)d_out;

    unsigned long long* tbits = (unsigned long long*)d_ws;
    float* wf = (float*)((char*)d_ws + (size_t)HW * 8);
    float* dot_p   = wf;                 // 36000
    float* dot_f   = wf + 36000;         // 36000
    float* sum_p   = wf + 72000;         // 600
    float* sum_neg = wf + 72600;         // 600
    float* pbox    = wf + 73200;         // 2400
    float* tsum    = wf + 75600;         // 60
    float* tbox    = wf + 75660;         // 240

    hipLaunchKernelGGL(hm_pack_tbits, dim3(HW / 256), dim3(256), 0, stream, tgt_masks, tbits);
    hipLaunchKernelGGL(hm_tgt_stats, dim3(TNUM), dim3(256), 0, stream, tgt_masks, tsum, tbox);
    hipLaunchKernelGGL(hm_pred_heavy, dim3(NPRED), dim3(256), 0, stream,
                       pred_masks, tbits, dot_p, dot_f, sum_p, sum_neg, pbox);
    hipLaunchKernelGGL(hm_combine, dim3((NPRED * TNUM + 255) / 256), dim3(256), 0, stream,
                       pred_logits, pred_boxes, tgt_boxes, tgt_ids,
                       dot_p, dot_f, sum_p, sum_neg, pbox, tsum, tbox, out);
}

// Round 3
// 115.980 us; speedup vs baseline: 5.2998x; 5.2998x over previous
//
#include <hip/hip_runtime.h>
#include <math.h>

#define HW    65536
#define TNUM  60
#define NPRED 600
#define NCLS  91
#define PS    16      // pixel splits
#define NTIL  38      // ceil(600/16) M-tiles of 16

typedef float f32x4 __attribute__((ext_vector_type(4)));
typedef short s16x8 __attribute__((ext_vector_type(8)));

// ================= K0a: target stats partials (cnt + masks_to_boxes) ==========
__global__ void hm_tgt_stats(const int* __restrict__ tm, float* __restrict__ tstat) {
    int j = blockIdx.x >> 3, chunk = blockIdx.x & 7;
    int tid = threadIdx.x;
    const int* row = tm + (size_t)j * HW + chunk * 8192;
    float cnt = 0.f, xmax = -INFINITY, ymax = -INFINITY, xmin = INFINITY, ymin = INFINITY;
    for (int i = tid; i < 8192; i += 256) {
        int pix = chunk * 8192 + i;
        float t = (float)row[i];
        float xf = (float)(pix & 255), yf = (float)(pix >> 8);
        float xm = t * xf, ym = t * yf;
        cnt += t;
        xmax = fmaxf(xmax, xm); ymax = fmaxf(ymax, ym);
        bool nz = (t != 0.f);
        xmin = fminf(xmin, nz ? xm : 1e8f);
        ymin = fminf(ymin, nz ? ym : 1e8f);
    }
#pragma unroll
    for (int o = 1; o < 64; o <<= 1) {
        cnt += __shfl_xor(cnt, o);
        xmax = fmaxf(xmax, __shfl_xor(xmax, o));
        ymax = fmaxf(ymax, __shfl_xor(ymax, o));
        xmin = fminf(xmin, __shfl_xor(xmin, o));
        ymin = fminf(ymin, __shfl_xor(ymin, o));
    }
    __shared__ float s[5][4];
    int w = tid >> 6;
    if ((tid & 63) == 0) { s[0][w]=cnt; s[1][w]=xmin; s[2][w]=ymin; s[3][w]=xmax; s[4][w]=ymax; }
    __syncthreads();
    if (tid == 0) {
        float* o = tstat + (size_t)(j * 8 + chunk) * 5;
        o[0] = s[0][0]+s[0][1]+s[0][2]+s[0][3];
        o[1] = fminf(fminf(s[1][0],s[1][1]),fminf(s[1][2],s[1][3]));
        o[2] = fminf(fminf(s[2][0],s[2][1]),fminf(s[2][2],s[2][3]));
        o[3] = fmaxf(fmaxf(s[3][0],s[3][1]),fmaxf(s[3][2],s[3][3]));
        o[4] = fmaxf(fmaxf(s[4][0],s[4][1]),fmaxf(s[4][2],s[4][3]));
    }
}

// ================= K0b: build Tpack in B-fragment order ======================
// Tpack ushort index: (kb*64 + j)*32 + g*8 + e   where pixel = kb*32 + g*8 + e
__global__ void hm_build_tpack(const int* __restrict__ tm, unsigned short* __restrict__ tp) {
    int bid = blockIdx.x;                 // 64 * 256 blocks
    int j = bid >> 8, chunk = bid & 255;
    int pix = chunk * 256 + threadIdx.x;
    unsigned short v = 0;
    if (j < TNUM) v = (tm[(size_t)j * HW + pix] != 0) ? (unsigned short)0x3F80 : (unsigned short)0;
    size_t idx = ((size_t)(pix >> 5) * 64 + j) * 32 + (size_t)((pix >> 3) & 3) * 8 + (pix & 7);
    tp[idx] = v;
}

// ================= K1: heavy fused MFMA kernel ===============================
__device__ inline void pix_proc(float x, int e, float xfb, float yf,
                                __bf16* P, __bf16* F,
                                float& sp, float& sn,
                                float& xM, float& yM, float& xm, float& ym) {
    float ex = __expf(x);
    float opex = 1.f + ex;
    float p = __fdividef(ex, opex);
    float spx = __logf(opex);      // -log(1-p)
    float spmx = spx - x;          // -log(p)
    float om = 1.f - p;
    float pos = 0.25f * om * om * spmx;
    float neg = 0.75f * p * p * spx;
    sp += p; sn += neg;
    float xf = xfb + (float)e;
    float xmsk = x * xf, ymsk = x * yf;
    xM = fmaxf(xM, xmsk); yM = fmaxf(yM, ymsk);
    bool nz = (x != 0.f);
    xm = fminf(xm, nz ? xmsk : 1e8f);
    ym = fminf(ym, nz ? ymsk : 1e8f);
    P[e] = (__bf16)p;
    F[e] = (__bf16)(pos - neg);
}

// grid: NTIL*PS blocks of 256. Block = (ntile, ps). Wave w owns pixels
// [ps*4096 + w*1024, +1024). A rows = ntile*16 .. +15 (one 16-row tile).
__launch_bounds__(256, 2)
__global__ void hm_heavy(const float* __restrict__ pm, const unsigned short* __restrict__ tp,
                         float* __restrict__ dots, float* __restrict__ stats) {
    int b = blockIdx.x;
    int ntile = b >> 4, ps = b & 15;
    int tid = threadIdx.x, w = tid >> 6, l = tid & 63, g = l >> 4, c = l & 15;
    int n0 = ntile * 16;
    int row = min(n0 + c, NPRED - 1);
    const float* A = pm + (size_t)row * HW;
    const s16x8* tpv = (const s16x8*)tp;
    int pb = ps * 4096 + w * 1024;

    f32x4 acc[4][2];
#pragma unroll
    for (int nt = 0; nt < 4; ++nt)
#pragma unroll
        for (int m = 0; m < 2; ++m) acc[nt][m] = (f32x4)0.f;

    float sp = 0.f, sn = 0.f;
    float xM = -INFINITY, yM = -INFINITY, xm = INFINITY, ym = INFINITY;

#pragma unroll 2
    for (int step = 0; step < 32; ++step) {
        int k0 = pb + step * 32;
        int kk = k0 + g * 8;
        float4 aa = *(const float4*)(A + kk);
        float4 ab = *(const float4*)(A + kk + 4);
        float yf = (float)(kk >> 8);
        float xfb = (float)(kk & 255);

        union { __bf16 h[8]; s16x8 v; } P, F;
        float x[8] = {aa.x, aa.y, aa.z, aa.w, ab.x, ab.y, ab.z, ab.w};
#pragma unroll
        for (int e = 0; e < 8; ++e)
            pix_proc(x[e], e, xfb, yf, P.h, F.h, sp, sn, xM, yM, xm, ym);

        int bbase = (k0 >> 5) * 256 + c * 4 + g;
#pragma unroll
        for (int nt = 0; nt < 4; ++nt) {
            s16x8 bf = tpv[bbase + nt * 64];
            acc[nt][0] = __builtin_amdgcn_mfma_f32_16x16x32_bf16(P.v, bf, acc[nt][0], 0, 0, 0);
            acc[nt][1] = __builtin_amdgcn_mfma_f32_16x16x32_bf16(F.v, bf, acc[nt][1], 0, 0, 0);
        }
    }

    // reduce per-row stats over the 4 g-groups (lanes c, c+16, c+32, c+48: same row)
#pragma unroll
    for (int o = 16; o <= 32; o <<= 1) {
        sp += __shfl_xor(sp, o); sn += __shfl_xor(sn, o);
        xM = fmaxf(xM, __shfl_xor(xM, o)); yM = fmaxf(yM, __shfl_xor(yM, o));
        xm = fminf(xm, __shfl_xor(xm, o)); ym = fminf(ym, __shfl_xor(ym, o));
    }

    __shared__ float ldsD[4][32][64];   // [wave][(nt*2+m)*4+r][lane] -- off <= 31
    __shared__ float ldsS[4][16][6];
#pragma unroll
    for (int nt = 0; nt < 4; ++nt)
#pragma unroll
        for (int m = 0; m < 2; ++m)
#pragma unroll
            for (int r = 0; r < 4; ++r)
                ldsD[w][(nt * 2 + m) * 4 + r][l] = acc[nt][m][r];
    if (l < 16) {
        ldsS[w][l][0] = sp; ldsS[w][l][1] = sn;
        ldsS[w][l][2] = xM; ldsS[w][l][3] = yM;
        ldsS[w][l][4] = xm; ldsS[w][l][5] = ym;
    }
    __syncthreads();

    // dots out: [b][mat][row16][col64]
    for (int idx = tid; idx < 2048; idx += 256) {
        int mat = idx >> 10, rl = (idx >> 6) & 15, col = idx & 63;
        int gg = rl >> 2, rg = rl & 3;
        int nt = col >> 4, cc = col & 15;
        int lane = gg * 16 + cc;
        int off = (nt * 2 + mat) * 4 + rg;
        float s = ldsD[0][off][lane] + ldsD[1][off][lane] + ldsD[2][off][lane] + ldsD[3][off][lane];
        dots[(size_t)b * 2048 + idx] = s;
    }
    // stats out: [b][row16][6]
    if (tid < 96) {
        int rr = tid / 6, s = tid % 6;
        float a0 = ldsS[0][rr][s], a1 = ldsS[1][rr][s], a2 = ldsS[2][rr][s], a3 = ldsS[3][rr][s];
        float r;
        if (s < 2)      r = a0 + a1 + a2 + a3;
        else if (s < 4) r = fmaxf(fmaxf(a0, a1), fmaxf(a2, a3));
        else            r = fminf(fminf(a0, a1), fminf(a2, a3));
        stats[(size_t)(b * 16 + rr) * 6 + s] = r;
    }
}

// ================= K2a: reduce pred stats over PS blocks =====================
__global__ void hm_pred_reduce(const float* __restrict__ stats, float* __restrict__ pstat) {
    int n = blockIdx.x;            // 600
    int l = threadIdx.x;           // 64
    int ntile = n >> 4, r = n & 15;
    int ps = l & 15;
    const float* sb = stats + ((size_t)((ntile * PS + ps) * 16 + r)) * 6;
    float v0 = sb[0], v1 = sb[1], v2 = sb[2], v3 = sb[3], v4 = sb[4], v5 = sb[5];
#pragma unroll
    for (int o = 1; o < 16; o <<= 1) {
        v0 += __shfl_xor(v0, o); v1 += __shfl_xor(v1, o);
        v2 = fmaxf(v2, __shfl_xor(v2, o)); v3 = fmaxf(v3, __shfl_xor(v3, o));
        v4 = fminf(v4, __shfl_xor(v4, o)); v5 = fminf(v5, __shfl_xor(v5, o));
    }
    if (l == 0) {
        float* o = pstat + (size_t)n * 6;
        o[0] = v0; o[1] = v1; o[2] = v2; o[3] = v3; o[4] = v4; o[5] = v5;
    }
}

// ================= helpers ===================================================
__device__ inline float giou2(float ax0, float ay0, float ax1, float ay1,
                              float bx0, float by0, float bx1, float by1) {
    float area1 = (ax1 - ax0) * (ay1 - ay0);
    float area2 = (bx1 - bx0) * (by1 - by0);
    float ltx = fmaxf(ax0, bx0), lty = fmaxf(ay0, by0);
    float rbx = fminf(ax1, bx1), rby = fminf(ay1, by1);
    float iw = fmaxf(rbx - ltx, 0.f), ih = fmaxf(rby - lty, 0.f);
    float inter = iw * ih;
    float uni = area1 + area2 - inter;
    float iou = inter / uni;
    float ex0 = fminf(ax0, bx0), ey0 = fminf(ay0, by0);
    float ex1 = fmaxf(ax1, bx1), ey1 = fmaxf(ay1, by1);
    float ew = fmaxf(ex1 - ex0, 0.f), eh = fmaxf(ey1 - ey0, 0.f);
    float ae = ew * eh;
    return iou - (ae - uni) / ae;
}

__device__ inline float giou_cxcywh(float acx, float acy, float aw, float ah,
                                    float bcx, float bcy, float bw, float bh) {
    return giou2(acx - 0.5f * aw, acy - 0.5f * ah, acx + 0.5f * aw, acy + 0.5f * ah,
                 bcx - 0.5f * bw, bcy - 0.5f * bh, bcx + 0.5f * bw, bcy + 0.5f * bh);
}

// ================= K3: final combine =========================================
__global__ void hm_combine(const float* __restrict__ pred_logits,
                           const float* __restrict__ pred_boxes,
                           const float* __restrict__ tgt_boxes,
                           const int* __restrict__ tgt_ids,
                           const float* __restrict__ dots,
                           const float* __restrict__ pstat,
                           const float* __restrict__ tstat,
                           float* __restrict__ out) {
    int idx = blockIdx.x * blockDim.x + threadIdx.x;
    if (idx >= NPRED * TNUM) return;
    int n = idx / TNUM, j = idx % TNUM;
    int ntile = n >> 4, r = n & 15;

    // reduce dot partials over PS pixel-splits; dots block layout [mat][row16][col64]
    const float* db = dots + (size_t)ntile * PS * 2048 + r * 64 + j;
    float dp = 0.f, df = 0.f;
#pragma unroll
    for (int ps = 0; ps < PS; ++ps) {
        dp += db[ps * 2048];
        df += db[ps * 2048 + 1024];
    }

    // reduce target stats over 8 chunks
    float tcnt = 0.f, txm = INFINITY, tym = INFINITY, txM = -INFINITY, tyM = -INFINITY;
#pragma unroll
    for (int k = 0; k < 8; ++k) {
        const float* tb = tstat + (size_t)(j * 8 + k) * 5;
        tcnt += tb[0];
        txm = fminf(txm, tb[1]); tym = fminf(tym, tb[2]);
        txM = fmaxf(txM, tb[3]); tyM = fmaxf(tyM, tb[4]);
    }

    const float* pp = pstat + (size_t)n * 6;
    float sum_p = pp[0], sum_neg = pp[1];
    float pxM = pp[2], pyM = pp[3], pxm = pp[4], pym = pp[5];

    // L1 bbox cost
    float4 ob = ((const float4*)pred_boxes)[n];
    float4 tb4 = ((const float4*)tgt_boxes)[j];
    float cbbox = fabsf(ob.x - tb4.x) + fabsf(ob.y - tb4.y) + fabsf(ob.z - tb4.z) + fabsf(ob.w - tb4.w);

    // GIoU cost (cxcywh boxes)
    float cgiou = -giou_cxcywh(ob.x, ob.y, ob.z, ob.w, tb4.x, tb4.y, tb4.z, tb4.w);

    // focal classification cost
    int id = tgt_ids[j];
    float lg = pred_logits[(size_t)n * NCLS + id];
    float e = __expf(lg);
    float pr = __fdividef(e, 1.f + e);
    float poscc = 0.25f * (1.f - pr) * (1.f - pr) * (-__logf(pr + 1e-8f));
    float negcc = 0.75f * pr * pr * (-__logf(1.f - pr + 1e-8f));
    float cclass = poscc - negcc;

    // GIoU on mask-derived boxes (faithfully fed through cxcywh conversion)
    float cm2b = -giou_cxcywh(pxm, pym, pxM, pyM, txm, tym, txM, tyM);

    // dice
    float un = sum_p + tcnt;
    float cdice = 1.f - (2.f * dp + 1e-5f) / (un + 1e-5f);

    // mask focal
    float cfocal = (df + sum_neg) * (1.0f / (float)HW);

    out[idx] = cbbox + cclass + cgiou + cm2b + cdice + cfocal;
}

// ================= launcher ==================================================
extern "C" void kernel_launch(void* const* d_in, const int* in_sizes, int n_in,
                              void* d_out, int out_size, void* d_ws, size_t ws_size,
                              hipStream_t stream) {
    const float* pred_logits = (const float*)d_in[0];
    const float* pred_boxes  = (const float*)d_in[1];
    const float* pred_masks  = (const float*)d_in[2];
    const float* tgt_boxes   = (const float*)d_in[3];
    const int*   tgt_ids     = (const int*)d_in[4];
    const int*   tgt_masks   = (const int*)d_in[5];
    float* out = (float*)d_out;

    char* wsb = (char*)d_ws;
    unsigned short* tpack = (unsigned short*)wsb;                      // 64*HW*2      = 8,388,608 B
    float* dots  = (float*)(wsb + 8388608);                            // 608*2048*4   = 4,980,736 B
    float* stats = (float*)(wsb + 8388608 + 4980736);                  // 608*16*6*4   = 233,472 B
    float* pstat = (float*)(wsb + 8388608 + 4980736 + 233472);         // 600*6*4      = 14,400 B
    float* tstat = (float*)(wsb + 8388608 + 4980736 + 233472 + 14400); // 480*5*4      = 9,600 B

    hipLaunchKernelGGL(hm_tgt_stats, dim3(TNUM * 8), dim3(256), 0, stream, tgt_masks, tstat);
    hipLaunchKernelGGL(hm_build_tpack, dim3(64 * 256), dim3(256), 0, stream, tgt_masks, tpack);
    hipLaunchKernelGGL(hm_heavy, dim3(NTIL * PS), dim3(256), 0, stream, pred_masks, tpack, dots, stats);
    hipLaunchKernelGGL(hm_pred_reduce, dim3(NPRED), dim3(64), 0, stream, stats, pstat);
    hipLaunchKernelGGL(hm_combine, dim3((NPRED * TNUM + 255) / 256), dim3(256), 0, stream,
                       pred_logits, pred_boxes, tgt_boxes, tgt_ids, dots, pstat, tstat, out);
}

// Round 4
// 94.066 us; speedup vs baseline: 6.5344x; 1.2330x over previous
//
#include <hip/hip_runtime.h>
#include <math.h>

#define HW    65536
#define TNUM  60
#define NPRED 600
#define NCLS  91
#define PS    32      // pixel splits
#define NTIL  38      // ceil(600/16) M-tiles of 16

typedef float f32x4 __attribute__((ext_vector_type(4)));
typedef short s16x8 __attribute__((ext_vector_type(8)));

// ================= K0a: target stats partials (cnt + masks_to_boxes) ==========
__global__ void hm_tgt_stats(const int* __restrict__ tm, float* __restrict__ tstat) {
    int j = blockIdx.x >> 3, chunk = blockIdx.x & 7;
    int tid = threadIdx.x;
    const int* row = tm + (size_t)j * HW + chunk * 8192;
    float cnt = 0.f, xmax = -INFINITY, ymax = -INFINITY, xmin = INFINITY, ymin = INFINITY;
    for (int i = tid; i < 8192; i += 256) {
        int pix = chunk * 8192 + i;
        float t = (float)row[i];
        float xf = (float)(pix & 255), yf = (float)(pix >> 8);
        float xm = t * xf, ym = t * yf;
        cnt += t;
        xmax = fmaxf(xmax, xm); ymax = fmaxf(ymax, ym);
        bool nz = (t != 0.f);
        xmin = fminf(xmin, nz ? xm : 1e8f);
        ymin = fminf(ymin, nz ? ym : 1e8f);
    }
#pragma unroll
    for (int o = 1; o < 64; o <<= 1) {
        cnt += __shfl_xor(cnt, o);
        xmax = fmaxf(xmax, __shfl_xor(xmax, o));
        ymax = fmaxf(ymax, __shfl_xor(ymax, o));
        xmin = fminf(xmin, __shfl_xor(xmin, o));
        ymin = fminf(ymin, __shfl_xor(ymin, o));
    }
    __shared__ float s[5][4];
    int w = tid >> 6;
    if ((tid & 63) == 0) { s[0][w]=cnt; s[1][w]=xmin; s[2][w]=ymin; s[3][w]=xmax; s[4][w]=ymax; }
    __syncthreads();
    if (tid == 0) {
        float* o = tstat + (size_t)(j * 8 + chunk) * 5;
        o[0] = s[0][0]+s[0][1]+s[0][2]+s[0][3];
        o[1] = fminf(fminf(s[1][0],s[1][1]),fminf(s[1][2],s[1][3]));
        o[2] = fminf(fminf(s[2][0],s[2][1]),fminf(s[2][2],s[2][3]));
        o[3] = fmaxf(fmaxf(s[3][0],s[3][1]),fmaxf(s[3][2],s[3][3]));
        o[4] = fmaxf(fmaxf(s[4][0],s[4][1]),fmaxf(s[4][2],s[4][3]));
    }
}

// ================= K0b: build Tpack in B-fragment order ======================
// Tpack ushort index: (kb*64 + j)*32 + g*8 + e   where pixel = kb*32 + g*8 + e
__global__ void hm_build_tpack(const int* __restrict__ tm, unsigned short* __restrict__ tp) {
    int bid = blockIdx.x;                 // 64 * 256 blocks
    int j = bid >> 8, chunk = bid & 255;
    int pix = chunk * 256 + threadIdx.x;
    unsigned short v = 0;
    if (j < TNUM) v = (tm[(size_t)j * HW + pix] != 0) ? (unsigned short)0x3F80 : (unsigned short)0;
    size_t idx = ((size_t)(pix >> 5) * 64 + j) * 32 + (size_t)((pix >> 3) & 3) * 8 + (pix & 7);
    tp[idx] = v;
}

// ================= K1: heavy fused MFMA kernel ===============================
__device__ inline void pix_proc(float x, int e, float xfb, float yf,
                                __bf16* P, __bf16* F,
                                float& sp, float& sn,
                                float& xM, float& yM, float& xm, float& ym) {
    float ex = __expf(x);
    float opex = 1.f + ex;
    float p = __fdividef(ex, opex);
    float spx = __logf(opex);      // -log(1-p)
    float spmx = spx - x;          // -log(p)
    float om = 1.f - p;
    float pos = (om * om) * (0.25f * spmx);
    float neg = (p * p) * (0.75f * spx);
    sp += p; sn += neg;
    float xf = xfb + (float)e;
    float xmsk = x * xf, ymsk = x * yf;
    xM = fmaxf(xM, xmsk); yM = fmaxf(yM, ymsk);
    bool nz = (x != 0.f);
    xm = fminf(xm, nz ? xmsk : 1e8f);
    ym = fminf(ym, nz ? ymsk : 1e8f);
    P[e] = (__bf16)p;
    F[e] = (__bf16)(pos - neg);
}

// grid: NTIL*PS blocks of 256. XCD-swizzled: xcd=id&7, q=id>>3,
// ntile=q%NTIL, ps=xcd + 8*(q/NTIL). All 38 blocks sharing a ps-slice of
// tpack land on one XCD -> 2MB tpack working set per XCD (L2-resident).
// Wave w owns pixels [ps*2048 + w*512, +512). A rows = ntile*16..+15.
__launch_bounds__(256, 4)
__global__ void hm_heavy(const float* __restrict__ pm, const unsigned short* __restrict__ tp,
                         float* __restrict__ dots, float* __restrict__ stats) {
    int id = blockIdx.x;
    int xcd = id & 7, q = id >> 3;
    int ntile = q % NTIL, ps = xcd + 8 * (q / NTIL);
    int bl = ntile * PS + ps;                 // logical block index
    int tid = threadIdx.x, w = tid >> 6, l = tid & 63, g = l >> 4, c = l & 15;
    int n0 = ntile * 16;
    int row = min(n0 + c, NPRED - 1);
    const float* A = pm + (size_t)row * HW;
    const s16x8* tpv = (const s16x8*)tp;
    int pb = ps * 2048 + w * 512;

    f32x4 acc[4][2];
#pragma unroll
    for (int nt = 0; nt < 4; ++nt)
#pragma unroll
        for (int m = 0; m < 2; ++m) acc[nt][m] = (f32x4)0.f;

    float sp = 0.f, sn = 0.f;
    float xM = -INFINITY, yM = -INFINITY, xm = INFINITY, ym = INFINITY;

#pragma unroll 2
    for (int step = 0; step < 16; ++step) {
        int k0 = pb + step * 32;
        int kk = k0 + g * 8;
        float4 aa = *(const float4*)(A + kk);
        float4 ab = *(const float4*)(A + kk + 4);
        float yf = (float)(kk >> 8);
        float xfb = (float)(kk & 255);

        union { __bf16 h[8]; s16x8 v; } P, F;
        float x[8] = {aa.x, aa.y, aa.z, aa.w, ab.x, ab.y, ab.z, ab.w};
#pragma unroll
        for (int e = 0; e < 8; ++e)
            pix_proc(x[e], e, xfb, yf, P.h, F.h, sp, sn, xM, yM, xm, ym);

        int bbase = (k0 >> 5) * 256 + c * 4 + g;
#pragma unroll
        for (int nt = 0; nt < 4; ++nt) {
            s16x8 bf = tpv[bbase + nt * 64];
            acc[nt][0] = __builtin_amdgcn_mfma_f32_16x16x32_bf16(P.v, bf, acc[nt][0], 0, 0, 0);
            acc[nt][1] = __builtin_amdgcn_mfma_f32_16x16x32_bf16(F.v, bf, acc[nt][1], 0, 0, 0);
        }
    }

    // reduce per-row stats over the 4 g-groups (lanes c, c+16, c+32, c+48: same row)
#pragma unroll
    for (int o = 16; o <= 32; o <<= 1) {
        sp += __shfl_xor(sp, o); sn += __shfl_xor(sn, o);
        xM = fmaxf(xM, __shfl_xor(xM, o)); yM = fmaxf(yM, __shfl_xor(yM, o));
        xm = fminf(xm, __shfl_xor(xm, o)); ym = fminf(ym, __shfl_xor(ym, o));
    }
    // per-wave stats straight to global: [bl][w][row16][6]
    if (l < 16) {
        float* so = stats + ((size_t)((bl * 4 + w) * 16 + l)) * 6;
        so[0] = sp; so[1] = sn; so[2] = xM; so[3] = yM; so[4] = xm; so[5] = ym;
    }

    __shared__ float ldsD[4][32][64];   // exactly 32 KiB
#pragma unroll
    for (int nt = 0; nt < 4; ++nt)
#pragma unroll
        for (int m = 0; m < 2; ++m)
#pragma unroll
            for (int r = 0; r < 4; ++r)
                ldsD[w][(nt * 2 + m) * 4 + r][l] = acc[nt][m][r];
    __syncthreads();

    // dots out: [bl][mat][row16][col64]
    for (int idx = tid; idx < 2048; idx += 256) {
        int mat = idx >> 10, rl = (idx >> 6) & 15, col = idx & 63;
        int gg = rl >> 2, rg = rl & 3;
        int nt = col >> 4, cc = col & 15;
        int lane = gg * 16 + cc;
        int off = (nt * 2 + mat) * 4 + rg;
        float s = ldsD[0][off][lane] + ldsD[1][off][lane] + ldsD[2][off][lane] + ldsD[3][off][lane];
        dots[(size_t)bl * 2048 + idx] = s;
    }
}

// ================= K2: reduce pred stats over PS*4 wave-partials =============
__global__ void hm_pred_reduce(const float* __restrict__ stats, float* __restrict__ pstat) {
    int n = blockIdx.x;            // 600
    int l = threadIdx.x;           // 64
    int ntile = n >> 4, r = n & 15;
    // chunk c in [0,128): stats idx = (ntile*128 + c)*16 + r
    const float* s0 = stats + ((size_t)(ntile * 128 + l) * 16 + r) * 6;
    const float* s1 = stats + ((size_t)(ntile * 128 + l + 64) * 16 + r) * 6;
    float v0 = s0[0] + s1[0];
    float v1 = s0[1] + s1[1];
    float v2 = fmaxf(s0[2], s1[2]);
    float v3 = fmaxf(s0[3], s1[3]);
    float v4 = fminf(s0[4], s1[4]);
    float v5 = fminf(s0[5], s1[5]);
#pragma unroll
    for (int o = 1; o < 64; o <<= 1) {
        v0 += __shfl_xor(v0, o); v1 += __shfl_xor(v1, o);
        v2 = fmaxf(v2, __shfl_xor(v2, o)); v3 = fmaxf(v3, __shfl_xor(v3, o));
        v4 = fminf(v4, __shfl_xor(v4, o)); v5 = fminf(v5, __shfl_xor(v5, o));
    }
    if (l == 0) {
        float* o = pstat + (size_t)n * 6;
        o[0] = v0; o[1] = v1; o[2] = v2; o[3] = v3; o[4] = v4; o[5] = v5;
    }
}

// ================= helpers ===================================================
__device__ inline float giou2(float ax0, float ay0, float ax1, float ay1,
                              float bx0, float by0, float bx1, float by1) {
    float area1 = (ax1 - ax0) * (ay1 - ay0);
    float area2 = (bx1 - bx0) * (by1 - by0);
    float ltx = fmaxf(ax0, bx0), lty = fmaxf(ay0, by0);
    float rbx = fminf(ax1, bx1), rby = fminf(ay1, by1);
    float iw = fmaxf(rbx - ltx, 0.f), ih = fmaxf(rby - lty, 0.f);
    float inter = iw * ih;
    float uni = area1 + area2 - inter;
    float iou = inter / uni;
    float ex0 = fminf(ax0, bx0), ey0 = fminf(ay0, by0);
    float ex1 = fmaxf(ax1, bx1), ey1 = fmaxf(ay1, by1);
    float ew = fmaxf(ex1 - ex0, 0.f), eh = fmaxf(ey1 - ey0, 0.f);
    float ae = ew * eh;
    return iou - (ae - uni) / ae;
}

__device__ inline float giou_cxcywh(float acx, float acy, float aw, float ah,
                                    float bcx, float bcy, float bw, float bh) {
    return giou2(acx - 0.5f * aw, acy - 0.5f * ah, acx + 0.5f * aw, acy + 0.5f * ah,
                 bcx - 0.5f * bw, bcy - 0.5f * bh, bcx + 0.5f * bw, bcy + 0.5f * bh);
}

// ================= K3: final combine =========================================
__global__ void hm_combine(const float* __restrict__ pred_logits,
                           const float* __restrict__ pred_boxes,
                           const float* __restrict__ tgt_boxes,
                           const int* __restrict__ tgt_ids,
                           const float* __restrict__ dots,
                           const float* __restrict__ pstat,
                           const float* __restrict__ tstat,
                           float* __restrict__ out) {
    int idx = blockIdx.x * blockDim.x + threadIdx.x;
    if (idx >= NPRED * TNUM) return;
    int n = idx / TNUM, j = idx % TNUM;
    int ntile = n >> 4, r = n & 15;

    // reduce dot partials over PS pixel-splits; per-block layout [mat][row16][col64]
    const float* db = dots + (size_t)ntile * PS * 2048 + r * 64 + j;
    float dp = 0.f, df = 0.f;
#pragma unroll
    for (int ps = 0; ps < PS; ++ps) {
        dp += db[ps * 2048];
        df += db[ps * 2048 + 1024];
    }

    // reduce target stats over 8 chunks
    float tcnt = 0.f, txm = INFINITY, tym = INFINITY, txM = -INFINITY, tyM = -INFINITY;
#pragma unroll
    for (int k = 0; k < 8; ++k) {
        const float* tb = tstat + (size_t)(j * 8 + k) * 5;
        tcnt += tb[0];
        txm = fminf(txm, tb[1]); tym = fminf(tym, tb[2]);
        txM = fmaxf(txM, tb[3]); tyM = fmaxf(tyM, tb[4]);
    }

    const float* pp = pstat + (size_t)n * 6;
    float sum_p = pp[0], sum_neg = pp[1];
    float pxM = pp[2], pyM = pp[3], pxm = pp[4], pym = pp[5];

    // L1 bbox cost
    float4 ob = ((const float4*)pred_boxes)[n];
    float4 tb4 = ((const float4*)tgt_boxes)[j];
    float cbbox = fabsf(ob.x - tb4.x) + fabsf(ob.y - tb4.y) + fabsf(ob.z - tb4.z) + fabsf(ob.w - tb4.w);

    // GIoU cost (cxcywh boxes)
    float cgiou = -giou_cxcywh(ob.x, ob.y, ob.z, ob.w, tb4.x, tb4.y, tb4.z, tb4.w);

    // focal classification cost
    int id = tgt_ids[j];
    float lg = pred_logits[(size_t)n * NCLS + id];
    float e = __expf(lg);
    float pr = __fdividef(e, 1.f + e);
    float poscc = 0.25f * (1.f - pr) * (1.f - pr) * (-__logf(pr + 1e-8f));
    float negcc = 0.75f * pr * pr * (-__logf(1.f - pr + 1e-8f));
    float cclass = poscc - negcc;

    // GIoU on mask-derived boxes (faithfully fed through cxcywh conversion)
    float cm2b = -giou_cxcywh(pxm, pym, pxM, pyM, txm, tym, txM, tyM);

    // dice
    float un = sum_p + tcnt;
    float cdice = 1.f - (2.f * dp + 1e-5f) / (un + 1e-5f);

    // mask focal
    float cfocal = (df + sum_neg) * (1.0f / (float)HW);

    out[idx] = cbbox + cclass + cgiou + cm2b + cdice + cfocal;
}

// ================= launcher ==================================================
extern "C" void kernel_launch(void* const* d_in, const int* in_sizes, int n_in,
                              void* d_out, int out_size, void* d_ws, size_t ws_size,
                              hipStream_t stream) {
    const float* pred_logits = (const float*)d_in[0];
    const float* pred_boxes  = (const float*)d_in[1];
    const float* pred_masks  = (const float*)d_in[2];
    const float* tgt_boxes   = (const float*)d_in[3];
    const int*   tgt_ids     = (const int*)d_in[4];
    const int*   tgt_masks   = (const int*)d_in[5];
    float* out = (float*)d_out;

    char* wsb = (char*)d_ws;
    unsigned short* tpack = (unsigned short*)wsb;          // 64*HW*2          = 8,388,608 B
    float* dots  = (float*)(wsb + 8388608);                // 1216*2048*4      = 9,961,472 B
    float* stats = (float*)(wsb + 18350080);               // 1216*4*16*6*4    = 1,867,776 B
    float* pstat = (float*)(wsb + 20217856);               // 600*6*4          = 14,400 B
    float* tstat = (float*)(wsb + 20232256);               // 480*5*4          = 9,600 B
                                                           // total ~20.24 MB

    hipLaunchKernelGGL(hm_tgt_stats, dim3(TNUM * 8), dim3(256), 0, stream, tgt_masks, tstat);
    hipLaunchKernelGGL(hm_build_tpack, dim3(64 * 256), dim3(256), 0, stream, tgt_masks, tpack);
    hipLaunchKernelGGL(hm_heavy, dim3(NTIL * PS), dim3(256), 0, stream, pred_masks, tpack, dots, stats);
    hipLaunchKernelGGL(hm_pred_reduce, dim3(NPRED), dim3(64), 0, stream, stats, pstat);
    hipLaunchKernelGGL(hm_combine, dim3((NPRED * TNUM + 255) / 256), dim3(256), 0, stream,
                       pred_logits, pred_boxes, tgt_boxes, tgt_ids, dots, pstat, tstat, out);
}